// Round 1
// baseline (329.321 us; speedup 1.0000x reference)
//
#include <hip/hip_runtime.h>
#include <hip/hip_bf16.h>
#include <cstdint>

typedef __bf16 bf16;
typedef __bf16 bf16x8 __attribute__((ext_vector_type(8)));
typedef float  f32x4  __attribute__((ext_vector_type(4)));

#define O_W1BT   0u          // 1024*1024 bf16 = 2 MB
#define O_C      2097152u    // 32*1024 f32    = 128 KB
#define O_E      2228224u    // 65536 f32      = 256 KB
#define O_ALPHA  2490368u    // 65536 f32      = 256 KB
#define O_HIDP   2752512u    // 8*32*1024 f32  = 1 MB
#define O_CTXP   3801088u    // 16*32*1024 f32 = 2 MB

// ---------------- hid_proj = hidden @ W1_hid, partials over d-chunks ----------------
__global__ void k_hid_partial(const float* __restrict__ hid, const float* __restrict__ W1,
                              float* __restrict__ hidp) {
    int e = blockIdx.x * 256 + threadIdx.x;   // grid.x = 4
    int dch = blockIdx.y;                     // grid.y = 8
    float acc[32];
#pragma unroll
    for (int b = 0; b < 32; ++b) acc[b] = 0.f;
    int d0 = dch * 128;
    for (int dd = 0; dd < 128; ++dd) {
        int d = d0 + dd;
        float w = W1[(size_t)(1024 + d) * 1024 + e];
#pragma unroll
        for (int b = 0; b < 32; ++b) acc[b] += hid[b * 1024 + d] * w;
    }
#pragma unroll
    for (int b = 0; b < 32; ++b) hidp[((size_t)dch * 32 + b) * 1024 + e] = acc[b];
}

__global__ void k_hid_reduce(const float* __restrict__ hidp, const float* __restrict__ b1,
                             float* __restrict__ cvec) {
    int i = blockIdx.x * 256 + threadIdx.x;   // 32768
    int e = i & 1023;
    float s = b1[e];
#pragma unroll
    for (int dch = 0; dch < 8; ++dch) s += hidp[(size_t)dch * 32768 + i];
    cvec[i] = s;
}

// ---------------- W1_enc (k x n) -> w1bt (n x k) bf16 ----------------
__global__ void k_w1t(const float* __restrict__ W1, bf16* __restrict__ w1bt) {
    __shared__ float tile[32][33];
    int tx = threadIdx.x, ty = threadIdx.y;   // (32,8)
    int bx = blockIdx.x, by = blockIdx.y;     // (32,32)
#pragma unroll
    for (int i = 0; i < 4; ++i) {
        int d = by * 32 + ty + i * 8;         // k index
        int e = bx * 32 + tx;                 // n index
        tile[ty + i * 8][tx] = W1[(size_t)d * 1024 + e];
    }
    __syncthreads();
#pragma unroll
    for (int i = 0; i < 4; ++i) {
        int e = bx * 32 + ty + i * 8;
        int d = by * 32 + tx;
        w1bt[(size_t)e * 1024 + d] = (bf16)tile[tx][ty + i * 8];
    }
}

// ---------------- fused GEMM + tanh + dot(w2) -> partial e (atomic) ----------------
__device__ inline float fast_tanh(float x) {
    float e2 = __expf(2.f * x);
    return 1.f - 2.f / (e2 + 1.f);
}

__global__ __launch_bounds__(256, 3) void k_gemm_e(
    const float* __restrict__ enc, const bf16* __restrict__ w1bt,
    const float* __restrict__ cvec, const float* __restrict__ w2,
    float* __restrict__ ebuf)
{
    __shared__ __align__(16) unsigned char smem[24 * 1024];  // A f32 16KB | B bf16 8KB
    const int t    = threadIdx.x;
    const int lane = t & 63;
    const int w    = t >> 6;
    const int wr   = w >> 1, wc = w & 1;
    const int l15  = lane & 15, g = lane >> 4;

    // XCD-aware swizzle: nwg=4096, 8 XCDs -> 512 contiguous ids per XCD, n-tile fastest
    unsigned raw = blockIdx.x;
    unsigned swz = (raw & 7u) * 512u + (raw >> 3);
    const int nt = swz & 7, mt = swz >> 3;
    const int m0 = mt * 128, n0 = nt * 128;
    const int b  = m0 >> 11;                  // 2048 rows per batch, 128 | 2048

    // --- staging source pointers (pre-swizzled global source, linear LDS dest) ---
    // A tile: 128 rows x 32 f32 (128 B/row). 4 calls x 256 threads x 16 B.
    // LDS[row][sp] (sp=16B slot 0..7) holds global slot sp ^ (row&7).
    int rowA  = (t >> 3);                     // call c adds c*32 (== 0 mod 8)
    int slotA = (t & 7) ^ (rowA & 7);
    const char* gA0 = (const char*)enc + (size_t)(m0 + rowA) * 4096 + slotA * 16;
    // B tile: 128 rows x 32 bf16 (64 B/row). 2 calls. slot sp holds global slot sp ^ ((row>>1)&3).
    int rowB  = (t >> 2);
    int slotB = (t & 3) ^ ((t >> 3) & 3);
    const char* gB0 = (const char*)w1bt + (size_t)(n0 + rowB) * 2048 + slotB * 16;

    // --- fragment LDS read offsets (base; derive the rest) ---
    int rowA0 = wr * 64 + l15;                         // m adds m*16 (== 0 mod 8)
    unsigned offA0 = (unsigned)rowA0 * 128 + ((((2 * g)) ^ (l15 & 7)) << 4);
    int rowB0 = wc * 64 + l15;                         // n adds n*16
    unsigned offB0 = 16384u + (unsigned)rowB0 * 64 + (((g ^ ((l15 >> 1) & 3))) << 4);

    f32x4 acc[4][4] = {};

    for (int kt = 0; kt < 32; ++kt) {
        const char* pa = gA0 + kt * 128;
        const char* pb = gB0 + kt * 64;
#pragma unroll
        for (int c = 0; c < 4; ++c)
            __builtin_amdgcn_global_load_lds(
                (const __attribute__((address_space(1))) unsigned int*)(pa + (size_t)c * 131072),
                (__attribute__((address_space(3))) unsigned int*)(smem + c * 4096 + w * 1024),
                16, 0, 0);
#pragma unroll
        for (int c = 0; c < 2; ++c)
            __builtin_amdgcn_global_load_lds(
                (const __attribute__((address_space(1))) unsigned int*)(pb + (size_t)c * 131072),
                (__attribute__((address_space(3))) unsigned int*)(smem + 16384 + c * 4096 + w * 1024),
                16, 0, 0);
        __syncthreads();   // drains vmcnt before barrier (compiler-inserted)

        bf16x8 af[4], bfr[4];
#pragma unroll
        for (int m = 0; m < 4; ++m) {
            unsigned o0 = offA0 + m * 2048;
            f32x4 lo = *(const f32x4*)(smem + o0);
            f32x4 hi = *(const f32x4*)(smem + (o0 ^ 16u));
            bf16x8 a;
            a[0] = (bf16)lo[0]; a[1] = (bf16)lo[1]; a[2] = (bf16)lo[2]; a[3] = (bf16)lo[3];
            a[4] = (bf16)hi[0]; a[5] = (bf16)hi[1]; a[6] = (bf16)hi[2]; a[7] = (bf16)hi[3];
            af[m] = a;
        }
#pragma unroll
        for (int n = 0; n < 4; ++n)
            bfr[n] = *(const bf16x8*)(smem + (offB0 + n * 1024));
#pragma unroll
        for (int m = 0; m < 4; ++m)
#pragma unroll
            for (int n = 0; n < 4; ++n)
                acc[m][n] = __builtin_amdgcn_mfma_f32_16x16x32_bf16(af[m], bfr[n], acc[m][n], 0, 0, 0);
        __syncthreads();
    }

    // --- epilogue: h = tanh(acc + c[b,col]); partial e[row] += h . w2 ---
    float cv[4], wv[4];
#pragma unroll
    for (int n = 0; n < 4; ++n) {
        int gcol = n0 + wc * 64 + n * 16 + l15;
        cv[n] = cvec[b * 1024 + gcol];
        wv[n] = w2[gcol];
    }
#pragma unroll
    for (int m = 0; m < 4; ++m) {
#pragma unroll
        for (int r = 0; r < 4; ++r) {
            float s = 0.f;
#pragma unroll
            for (int n = 0; n < 4; ++n)
                s += fast_tanh(acc[m][n][r] + cv[n]) * wv[n];
            s += __shfl_xor(s, 1); s += __shfl_xor(s, 2);
            s += __shfl_xor(s, 4); s += __shfl_xor(s, 8);
            if (l15 == 0) {
                int grow = m0 + wr * 64 + m * 16 + g * 4 + r;
                atomicAdd(&ebuf[grow], s);
            }
        }
    }
}

// ---------------- softmax over S per batch ----------------
__global__ void k_softmax(const float* __restrict__ ebuf, float* __restrict__ alpha) {
    int bb = blockIdx.x, t = threadIdx.x;     // 32 blocks x 256
    __shared__ float red[4], red2[4];
    float v[8];
    float mx = -1e30f;
#pragma unroll
    for (int i = 0; i < 8; ++i) { v[i] = ebuf[bb * 2048 + i * 256 + t]; mx = fmaxf(mx, v[i]); }
    for (int o = 32; o > 0; o >>= 1) mx = fmaxf(mx, __shfl_xor(mx, o));
    if ((t & 63) == 0) red[t >> 6] = mx;
    __syncthreads();
    mx = fmaxf(fmaxf(red[0], red[1]), fmaxf(red[2], red[3]));
    float sum = 0.f;
#pragma unroll
    for (int i = 0; i < 8; ++i) { v[i] = __expf(v[i] - mx); sum += v[i]; }
    for (int o = 32; o > 0; o >>= 1) sum += __shfl_xor(sum, o);
    if ((t & 63) == 0) red2[t >> 6] = sum;
    __syncthreads();
    sum = red2[0] + red2[1] + red2[2] + red2[3];
    float inv = 1.f / sum;
#pragma unroll
    for (int i = 0; i < 8; ++i) alpha[bb * 2048 + i * 256 + t] = v[i] * inv;
}

// ---------------- context = sum_s alpha * enc, partials then reduce ----------------
__global__ void k_ctx_partial(const float* __restrict__ enc, const float* __restrict__ alpha,
                              float* __restrict__ ctxp) {
    int bid = blockIdx.x;                     // 512 = 32 b x 16 s-chunks
    int bb = bid >> 4, sc = bid & 15;
    int t = threadIdx.x;                      // 256, each owns 4 floats of D
    __shared__ float al[128];
    if (t < 128) al[t] = alpha[bb * 2048 + sc * 128 + t];
    __syncthreads();
    f32x4 acc = {0.f, 0.f, 0.f, 0.f};
    const f32x4* base = (const f32x4*)(enc + ((size_t)bb * 2048 + sc * 128) * 1024) + t;
    for (int s = 0; s < 128; ++s) {
        f32x4 vv = base[(size_t)s * 256];
        acc += vv * al[s];
    }
    *((f32x4*)(ctxp + (size_t)bid * 1024) + t) = acc;
}

__global__ void k_ctx_reduce(const float* __restrict__ ctxp, float* __restrict__ out) {
    int i = blockIdx.x * 256 + threadIdx.x;   // 32768
    int bb = i >> 10, d = i & 1023;
    float s = 0.f;
#pragma unroll
    for (int sc = 0; sc < 16; ++sc) s += ctxp[((size_t)(bb * 16 + sc)) * 1024 + d];
    out[i] = s;
}

extern "C" void kernel_launch(void* const* d_in, const int* in_sizes, int n_in,
                              void* d_out, int out_size, void* d_ws, size_t ws_size,
                              hipStream_t stream) {
    const float* hid = (const float*)d_in[0];
    const float* enc = (const float*)d_in[1];
    const float* W1  = (const float*)d_in[2];
    const float* b1  = (const float*)d_in[3];
    const float* w2  = (const float*)d_in[4];
    float* out = (float*)d_out;
    char* ws = (char*)d_ws;

    bf16*  w1bt  = (bf16*)(ws + O_W1BT);
    float* cvec  = (float*)(ws + O_C);
    float* ebuf  = (float*)(ws + O_E);
    float* alpha = (float*)(ws + O_ALPHA);
    float* hidp  = (float*)(ws + O_HIDP);
    float* ctxp  = (float*)(ws + O_CTXP);

    hipMemsetAsync(ebuf, 0, 65536 * sizeof(float), stream);
    k_hid_partial<<<dim3(4, 8), 256, 0, stream>>>(hid, W1, hidp);
    k_w1t<<<dim3(32, 32), dim3(32, 8), 0, stream>>>(W1, w1bt);
    k_hid_reduce<<<128, 256, 0, stream>>>(hidp, b1, cvec);
    k_gemm_e<<<4096, 256, 0, stream>>>(enc, w1bt, cvec, w2, ebuf);
    k_softmax<<<32, 256, 0, stream>>>(ebuf, alpha);
    k_ctx_partial<<<512, 256, 0, stream>>>(enc, alpha, ctxp);
    k_ctx_reduce<<<128, 256, 0, stream>>>(ctxp, out);
}